// Round 4
// baseline (329.561 us; speedup 1.0000x reference)
//
#include <hip/hip_runtime.h>

#define HDIM 128

typedef __bf16 bf16_t;
typedef bf16_t bf16x8 __attribute__((ext_vector_type(8)));
typedef float  f32x4  __attribute__((ext_vector_type(4)));

__device__ __forceinline__ unsigned short f2bf_rne(float f) {
    unsigned int u = __float_as_uint(f);
    u += 0x7fffu + ((u >> 16) & 1u);   // round-to-nearest-even
    return (unsigned short)(u >> 16);
}
__device__ __forceinline__ unsigned int pk_bf2(float a, float b) {
    return (unsigned int)f2bf_rne(a) | ((unsigned int)f2bf_rne(b) << 16);
}

// W1 [2*128 k][128 n] fp32 -> Wt [2][n=128][k=128] bf16 (n-major, k-contiguous)
__global__ __launch_bounds__(256) void convert_w1(
    const float* __restrict__ W1, unsigned short* __restrict__ Wt)
{
    const int o = blockIdx.x * 256 + threadIdx.x;     // 0..32767
    const int g = o >> 14, rem = o & 16383, n = rem >> 7, k = rem & 127;
    Wt[o] = f2bf_rne(W1[g * 16384 + k * 128 + n]);
}

// C_bf16[M,128] = bf16(Z[M,128]) @ bf16(W[128,128]) (+ b1 if second problem).
// 64 rows/block, 4 waves; wave w owns rows w*16..w*16+15, all 128 cols.
// MFMA operand swap: A-op = W^T frag (from global/L1), B-op = Z frag (from LDS)
// so D: col'=lane&15 = Z-row, row'=quad*4+reg = 4 contiguous out-cols -> 8B stores.
#define ZP 136   // LDS pitch in shorts (272 B: 16B-aligned, bank-spread)
__global__ __launch_bounds__(256) void node_gemm_mfma(
    const float* __restrict__ Zs, const float* __restrict__ Zd,
    const unsigned short* __restrict__ Wt, const float* __restrict__ b1,
    unsigned short* __restrict__ Abuf, unsigned short* __restrict__ Bbuf,
    int M, int gb)
{
    __shared__ unsigned short zs[64 * ZP];    // Z tile, bf16, k-contiguous rows

    const bool second = (blockIdx.x >= gb);
    const float* __restrict__ Z          = second ? Zd : Zs;
    const unsigned short* __restrict__ W = Wt + (second ? 128 * 128 : 0);
    unsigned short* __restrict__ C       = second ? Bbuf : Abuf;
    const int bx   = second ? (blockIdx.x - gb) : blockIdx.x;
    const int row0 = bx * 64;
    const int t    = threadIdx.x;

    // ---- stage Z (64x128 fp32 -> bf16 LDS), coalesced float4 loads ----
    #pragma unroll
    for (int j = 0; j < 8; ++j) {
        const int u   = t + 256 * j;       // 0..2047 float4-chunks
        const int row = u >> 5;            // 0..63
        const int c4  = u & 31;            // float4 index in row
        int rg = row0 + row; if (rg >= M) rg = M - 1;
        const float4 v = *reinterpret_cast<const float4*>(Z + (size_t)rg * HDIM + c4 * 4);
        uint2 p; p.x = pk_bf2(v.x, v.y); p.y = pk_bf2(v.z, v.w);
        *reinterpret_cast<uint2*>(zs + row * ZP + c4 * 4) = p;
    }
    __syncthreads();

    const int lane = t & 63;
    const int wave = t >> 6;
    const int m    = lane & 15;     // Z-row within wave's 16 / W-col within tile
    const int quad = lane >> 4;

    // Z fragments: 4 k-steps, reused across all 8 col-tiles
    bf16x8 zf[4];
    {
        const unsigned short* zp = zs + (wave * 16 + m) * ZP + quad * 8;
        #pragma unroll
        for (int ks = 0; ks < 4; ++ks)
            zf[ks] = *reinterpret_cast<const bf16x8*>(zp + ks * 32);
    }

    f32x4 acc[8] = {};
    #pragma unroll
    for (int ct = 0; ct < 8; ++ct) {
        const unsigned short* wp = W + (ct * 16 + m) * HDIM + quad * 8;
        #pragma unroll
        for (int ks = 0; ks < 4; ++ks) {
            const bf16x8 wf = *reinterpret_cast<const bf16x8*>(wp + ks * 32);
            acc[ct] = __builtin_amdgcn_mfma_f32_16x16x32_bf16(wf, zf[ks], acc[ct], 0, 0, 0);
        }
    }

    // ---- epilogue: +bias, fp32->bf16, 8-byte stores ----
    const int grow = row0 + wave * 16 + m;
    if (grow < M) {
        unsigned short* crow = C + (size_t)grow * HDIM;
        #pragma unroll
        for (int ct = 0; ct < 8; ++ct) {
            const int col = ct * 16 + quad * 4;
            float4 bv = make_float4(0.f, 0.f, 0.f, 0.f);
            if (second) bv = *reinterpret_cast<const float4*>(b1 + col);
            uint2 o;
            o.x = pk_bf2(acc[ct][0] + bv.x, acc[ct][1] + bv.y);
            o.y = pk_bf2(acc[ct][2] + bv.z, acc[ct][3] + bv.w);
            *reinterpret_cast<uint2*>(crow + col) = o;
        }
    }
}

// out[e] = relu(A[row[e]] + B[col[e]]) . W2 + b2, A/B bf16 (b1 folded into B).
// 16 lanes per edge; lane handles 8 features (16 B load/operand).
__global__ __launch_bounds__(256) void edge_decode_bf16(
    const unsigned short* __restrict__ A, const unsigned short* __restrict__ Bm,
    const int* __restrict__ idx,   // [2*E]: rows then cols
    const float* __restrict__ W2, const float* __restrict__ b2,
    float* __restrict__ out, int E)
{
    const int t   = threadIdx.x;
    const int sub = t & 15;
    const int grp = t >> 4;

    float w2r[8];
    #pragma unroll
    for (int i = 0; i < 8; ++i) w2r[i] = W2[sub * 8 + i];
    const float b2s = b2[0];

    const int stride = gridDim.x * 16;
    for (int e = blockIdx.x * 16 + grp; e < E; e += stride) {
        const int r = idx[e];
        const int c = idx[E + e];
        const uint4 av = *reinterpret_cast<const uint4*>(A  + (size_t)r * HDIM + sub * 8);
        const uint4 bv = *reinterpret_cast<const uint4*>(Bm + (size_t)c * HDIM + sub * 8);

        float s = 0.f;
        #pragma unroll
        for (int i = 0; i < 4; ++i) {
            const unsigned int ua = (&av.x)[i];
            const unsigned int ub = (&bv.x)[i];
            s += fmaxf(__uint_as_float(ua << 16)         + __uint_as_float(ub << 16),         0.f) * w2r[2 * i];
            s += fmaxf(__uint_as_float(ua & 0xffff0000u) + __uint_as_float(ub & 0xffff0000u), 0.f) * w2r[2 * i + 1];
        }
        s += __shfl_xor(s, 1);
        s += __shfl_xor(s, 2);
        s += __shfl_xor(s, 4);
        s += __shfl_xor(s, 8);
        if (sub == 0) out[e] = s + b2s;
    }
}

extern "C" void kernel_launch(void* const* d_in, const int* in_sizes, int n_in,
                              void* d_out, int out_size, void* d_ws, size_t ws_size,
                              hipStream_t stream)
{
    const float* z_src = (const float*)d_in[0];
    const float* z_dst = (const float*)d_in[1];
    const int*   eidx  = (const int*)d_in[2];
    const float* W1    = (const float*)d_in[3];
    const float* b1    = (const float*)d_in[4];
    const float* W2    = (const float*)d_in[5];
    const float* b2    = (const float*)d_in[6];
    float*       outp  = (float*)d_out;

    const int Nn = in_sizes[0] / HDIM;    // 100000
    const int E  = in_sizes[2] / 2;       // 2000000

    unsigned short* Abuf = (unsigned short*)d_ws;
    unsigned short* Bbuf = Abuf + (size_t)Nn * HDIM;
    unsigned short* Wt   = Bbuf + (size_t)Nn * HDIM;

    convert_w1<<<128, 256, 0, stream>>>(W1, Wt);

    const int gb = (Nn + 63) / 64;
    node_gemm_mfma<<<2 * gb, 256, 0, stream>>>(z_src, z_dst, Wt, b1, Abuf, Bbuf, Nn, gb);

    edge_decode_bf16<<<8192, 256, 0, stream>>>(Abuf, Bbuf, eidx, W2, b2, outp, E);
}

// Round 6
// 292.222 us; speedup vs baseline: 1.1278x; 1.1278x over previous
//
#include <hip/hip_runtime.h>

#define HDIM 128
#define ZP   136      // LDS pitch in shorts for W (272 B: 16B-aligned, 4-bank row skew)
#define NBH  512      // blocks per half in the gemm

typedef __bf16 bf16_t;
typedef bf16_t bf16x8 __attribute__((ext_vector_type(8)));
typedef float  f32x4  __attribute__((ext_vector_type(4)));

__device__ __forceinline__ unsigned short f2bf_rne(float f) {
    unsigned int u = __float_as_uint(f);
    u += 0x7fffu + ((u >> 16) & 1u);   // round-to-nearest-even
    return (unsigned short)(u >> 16);
}
__device__ __forceinline__ unsigned int pk_bf2(float a, float b) {
    return (unsigned int)f2bf_rne(a) | ((unsigned int)f2bf_rne(b) << 16);
}

// W1 [2*128 k][128 n] fp32 -> Wt [2][n=128][k=128] bf16 (n-major, k-contiguous)
__global__ __launch_bounds__(256) void convert_w1(
    const float* __restrict__ W1, unsigned short* __restrict__ Wt)
{
    const int o = blockIdx.x * 256 + threadIdx.x;     // 0..32767
    const int g = o >> 14, rem = o & 16383, n = rem >> 7, k = rem & 127;
    Wt[o] = f2bf_rne(W1[g * 16384 + k * 128 + n]);
}

// C_bf16[M,128] = bf16(Z[M,128]) @ bf16(W[128,128]) (+ b1 if second half).
// 1024 blocks: [0,NBH) -> (Zs -> Abuf), [NBH,2*NBH) -> (Zd -> Bbuf, +b1).
// W staged to LDS ONCE per block; grid-stride over 64-row tiles; Z goes
// global -> registers (B-op fragment is naturally per-lane-row), no loop barrier.
__global__ __launch_bounds__(256) void node_gemm_v3(
    const float* __restrict__ Zs, const float* __restrict__ Zd,
    const unsigned short* __restrict__ Wt, const float* __restrict__ b1,
    unsigned short* __restrict__ Abuf, unsigned short* __restrict__ Bbuf,
    int M)
{
    __shared__ unsigned short wlds[128 * ZP];   // 34 KB

    const bool second = (blockIdx.x >= NBH);
    const float* __restrict__ Z          = second ? Zd : Zs;
    const unsigned short* __restrict__ W = Wt + (second ? 128 * 128 : 0);
    unsigned short* __restrict__ C       = second ? Bbuf : Abuf;
    const int bx = second ? (blockIdx.x - NBH) : blockIdx.x;
    const int t  = threadIdx.x;

    // ---- stage W (128 rows x 128 k, bf16) once; row n at pitch ZP ----
    // 128 rows x 16 uint4-chunks/row = 2048 chunks; 256 threads x 8 iters.
    #pragma unroll
    for (int j = 0; j < 8; ++j) {
        const int u = t + 256 * j;          // 0..2047
        const int n = u >> 4, c = u & 15;   // row 0..127, chunk 0..15
        const uint4 v = *reinterpret_cast<const uint4*>(W + n * 128 + c * 8);
        *reinterpret_cast<uint4*>(wlds + n * ZP + c * 8) = v;
    }
    __syncthreads();   // the only barrier

    const int lane = t & 63;
    const int wave = t >> 6;
    const int m    = lane & 15;     // Z row within wave's 16 / D col group
    const int quad = lane >> 4;

    const int ntiles = (M + 63) >> 6;
    for (int tile = bx; tile < ntiles; tile += NBH) {
        const int row0 = tile * 64;
        const int r    = row0 + wave * 16 + m;
        const int rc   = (r < M) ? r : (M - 1);
        const float* zrow = Z + (size_t)rc * HDIM;

        f32x4 acc[8] = {};
        #pragma unroll
        for (int ks = 0; ks < 4; ++ks) {
            // B-op fragment: Z[rc][ks*32 + quad*8 .. +8] fp32 -> bf16x8
            const float4 v0 = *reinterpret_cast<const float4*>(zrow + ks * 32 + quad * 8);
            const float4 v1 = *reinterpret_cast<const float4*>(zrow + ks * 32 + quad * 8 + 4);
            union { unsigned int u[4]; bf16x8 h; } zf;
            zf.u[0] = pk_bf2(v0.x, v0.y);
            zf.u[1] = pk_bf2(v0.z, v0.w);
            zf.u[2] = pk_bf2(v1.x, v1.y);
            zf.u[3] = pk_bf2(v1.z, v1.w);
            #pragma unroll
            for (int ct = 0; ct < 8; ++ct) {
                const bf16x8 wf = *reinterpret_cast<const bf16x8*>(
                    wlds + (ct * 16 + m) * ZP + ks * 32 + quad * 8);
                acc[ct] = __builtin_amdgcn_mfma_f32_16x16x32_bf16(wf, zf.h, acc[ct], 0, 0, 0);
            }
        }

        // ---- epilogue: +bias, fp32->bf16, 8-B stores (D: col=m -> Z row,
        //      rows quad*4+reg -> 4 contiguous out cols) ----
        if (r < M) {
            unsigned short* crow = C + (size_t)r * HDIM;
            #pragma unroll
            for (int ct = 0; ct < 8; ++ct) {
                const int col = ct * 16 + quad * 4;
                float4 bv = make_float4(0.f, 0.f, 0.f, 0.f);
                if (second) bv = *reinterpret_cast<const float4*>(b1 + col);
                uint2 o;
                o.x = pk_bf2(acc[ct][0] + bv.x, acc[ct][1] + bv.y);
                o.y = pk_bf2(acc[ct][2] + bv.z, acc[ct][3] + bv.w);
                *reinterpret_cast<uint2*>(crow + col) = o;
            }
        }
    }
}

// out[e] = relu(A[row[e]] + B[col[e]]) . W2 + b2, A/B bf16 (b1 folded into B).
// 16 lanes per edge; lane handles 8 features (16 B load/operand).
__global__ __launch_bounds__(256) void edge_decode_bf16(
    const unsigned short* __restrict__ A, const unsigned short* __restrict__ Bm,
    const int* __restrict__ idx,   // [2*E]: rows then cols
    const float* __restrict__ W2, const float* __restrict__ b2,
    float* __restrict__ out, int E)
{
    const int t   = threadIdx.x;
    const int sub = t & 15;
    const int grp = t >> 4;

    float w2r[8];
    #pragma unroll
    for (int i = 0; i < 8; ++i) w2r[i] = W2[sub * 8 + i];
    const float b2s = b2[0];

    const int stride = gridDim.x * 16;
    for (int e = blockIdx.x * 16 + grp; e < E; e += stride) {
        const int r = idx[e];
        const int c = idx[E + e];
        const uint4 av = *reinterpret_cast<const uint4*>(A  + (size_t)r * HDIM + sub * 8);
        const uint4 bv = *reinterpret_cast<const uint4*>(Bm + (size_t)c * HDIM + sub * 8);

        float s = 0.f;
        #pragma unroll
        for (int i = 0; i < 4; ++i) {
            const unsigned int ua = (&av.x)[i];
            const unsigned int ub = (&bv.x)[i];
            s += fmaxf(__uint_as_float(ua << 16)         + __uint_as_float(ub << 16),         0.f) * w2r[2 * i];
            s += fmaxf(__uint_as_float(ua & 0xffff0000u) + __uint_as_float(ub & 0xffff0000u), 0.f) * w2r[2 * i + 1];
        }
        s += __shfl_xor(s, 1);
        s += __shfl_xor(s, 2);
        s += __shfl_xor(s, 4);
        s += __shfl_xor(s, 8);
        if (sub == 0) out[e] = s + b2s;
    }
}

extern "C" void kernel_launch(void* const* d_in, const int* in_sizes, int n_in,
                              void* d_out, int out_size, void* d_ws, size_t ws_size,
                              hipStream_t stream)
{
    const float* z_src = (const float*)d_in[0];
    const float* z_dst = (const float*)d_in[1];
    const int*   eidx  = (const int*)d_in[2];
    const float* W1    = (const float*)d_in[3];
    const float* b1    = (const float*)d_in[4];
    const float* W2    = (const float*)d_in[5];
    const float* b2    = (const float*)d_in[6];
    float*       outp  = (float*)d_out;

    const int Nn = in_sizes[0] / HDIM;    // 100000
    const int E  = in_sizes[2] / 2;       // 2000000

    unsigned short* Abuf = (unsigned short*)d_ws;
    unsigned short* Bbuf = Abuf + (size_t)Nn * HDIM;
    unsigned short* Wt   = Bbuf + (size_t)Nn * HDIM;

    convert_w1<<<128, 256, 0, stream>>>(W1, Wt);

    node_gemm_v3<<<2 * NBH, 256, 0, stream>>>(z_src, z_dst, Wt, b1, Abuf, Bbuf, Nn);

    edge_decode_bf16<<<8192, 256, 0, stream>>>(Abuf, Bbuf, eidx, W2, b2, outp, E);
}